// Round 7
// baseline (246.550 us; speedup 1.0000x reference)
//
#include <hip/hip_runtime.h>
#include <hip/hip_bf16.h>
#include <stdint.h>

#define H_DIM 4096
#define I_DIM 11008
#define NGH   32    // H/128 groups (gate/up)
#define NGI   86    // I/128 groups (down)
#define HP    (H_DIM/8)   // 512 packed words per gate/up row
#define IP    (I_DIM/8)   // 1376 packed words per down row

typedef __attribute__((ext_vector_type(8))) short short8;
typedef __attribute__((ext_vector_type(4))) short s16x4;
typedef __attribute__((ext_vector_type(4))) float f32x4;
typedef __attribute__((ext_vector_type(4))) int   i32x4;

static __device__ __forceinline__ short f2bf(float f) {
  union { __hip_bfloat16 b; short s; } u;
  u.b = __float2bfloat16(f);
  return u.s;
}

__global__ void xcvt_kernel(const float* __restrict__ x, short* __restrict__ xb) {
  int i = (blockIdx.x * 256 + threadIdx.x) * 4;
  f32x4 v = *(const f32x4*)(x + i);
  s16x4 o;
  o[0] = f2bf(v[0]); o[1] = f2bf(v[1]); o[2] = f2bf(v[2]); o[3] = f2bf(v[3]);
  *(s16x4*)(xb + i) = o;
}

// ---- pack: 8 int32 codes -> 1 int32 of nibbles. Pure streaming read. ----
__global__ __launch_bounds__(256) void pack_kernel(const int* __restrict__ src,
                                                   int* __restrict__ dst) {
  const int o = blockIdx.x * 256 + threadIdx.x;
  const int* s = src + (size_t)o * 8;
  i32x4 a = *(const i32x4*)s;
  i32x4 b = *(const i32x4*)(s + 4);
  int p = (a[0] & 15)        | ((a[1] & 15) << 4)  | ((a[2] & 15) << 8)  | ((a[3] & 15) << 12)
        | ((b[0] & 15) << 16) | ((b[1] & 15) << 20) | ((b[2] & 15) << 24) | ((b[3] & 15) << 28);
  dst[o] = p;
}

// ---------------- packed phase1: gate+up GEMM + SwiGLU ----------------
// Grid: I/16 blocks x 512 thr (8 waves). Wave w: K-seg of 512 (64 packed words).
__global__ __launch_bounds__(512, 4) void phase1p_kernel(
    const short* __restrict__ xb,
    const int* __restrict__ gp, const float* __restrict__ gsc, const float* __restrict__ gze,
    const int* __restrict__ up, const float* __restrict__ usc, const float* __restrict__ uze,
    short* __restrict__ hb)
{
  __shared__ float red[8][4][4][64];   // 32 KB, reused for G then U
  const int n0   = blockIdx.x * 16;
  const int w    = threadIdx.x >> 6;
  const int l    = threadIdx.x & 63;
  const int col  = l & 15;
  const int krow = l >> 4;
  const int i    = n0 + col;

  const int*   gpr = gp + (size_t)i * HP;
  const int*   upr = up + (size_t)i * HP;
  const float* gsr = gsc + (size_t)i * NGH;
  const float* gzr = gze + (size_t)i * NGH;
  const float* usr = usc + (size_t)i * NGH;
  const float* uzr = uze + (size_t)i * NGH;

  f32x4 accG[4], accU[4];
#pragma unroll
  for (int c = 0; c < 4; ++c)
#pragma unroll
    for (int r = 0; r < 4; ++r) { accG[c][r] = 0.f; accU[c][r] = 0.f; }

  const int wb = w * 64;               // packed word base of this wave's K-seg

  // 1-deep prefetch of the packed weight words
  int qg = gpr[wb + krow];
  int qu = upr[wb + krow];

#pragma unroll 1
  for (int g = 0; g < 4; ++g) {
    const int gg = w * 4 + g;
    const float sg = gsr[gg], zg = gzr[gg] * sg;   // w = q*s - z*s
    const float su = usr[gg], zu = uzr[gg] * su;
#pragma unroll
    for (int ks = 0; ks < 4; ++ks) {
      const int cg = qg, cu = qu;
      const int wloc = g * 16 + ks * 4;
      {
        const int nw = wb + ((wloc + 4) & 63) + krow;   // wraps; in-bounds
        qg = gpr[nw];
        qu = upr[nw];
      }
      const int kg = w * 512 + g * 128 + ks * 32 + krow * 8;
      short8 a[4];
#pragma unroll
      for (int c = 0; c < 4; ++c)
        a[c] = *(const short8*)(xb + (size_t)(c * 16 + col) * H_DIM + kg);
      short8 bg, bu;
#pragma unroll
      for (int j = 0; j < 8; ++j) {
        bg[j] = f2bf((float)((cg >> (4 * j)) & 15) * sg - zg);
        bu[j] = f2bf((float)((cu >> (4 * j)) & 15) * su - zu);
      }
#pragma unroll
      for (int c = 0; c < 4; ++c) {
        accG[c] = __builtin_amdgcn_mfma_f32_16x16x32_bf16(a[c], bg, accG[c], 0, 0, 0);
        accU[c] = __builtin_amdgcn_mfma_f32_16x16x32_bf16(a[c], bu, accU[c], 0, 0, 0);
      }
    }
  }

  const int c2 = threadIdx.x >> 7;
  const int rh = (threadIdx.x >> 6) & 1;
  const int ll = threadIdx.x & 63;

#pragma unroll
  for (int c = 0; c < 4; ++c)
#pragma unroll
    for (int r = 0; r < 4; ++r)
      red[w][c][r][l] = accG[c][r];
  __syncthreads();
  float gsum[2];
#pragma unroll
  for (int rr = 0; rr < 2; ++rr) {
    const int r = rh * 2 + rr;
    float s = 0.f;
#pragma unroll
    for (int ww = 0; ww < 8; ++ww) s += red[ww][c2][r][ll];
    gsum[rr] = s;
  }
  __syncthreads();

#pragma unroll
  for (int c = 0; c < 4; ++c)
#pragma unroll
    for (int r = 0; r < 4; ++r)
      red[w][c][r][l] = accU[c][r];
  __syncthreads();
#pragma unroll
  for (int rr = 0; rr < 2; ++rr) {
    const int r = rh * 2 + rr;
    float us = 0.f;
#pragma unroll
    for (int ww = 0; ww < 8; ++ww) us += red[ww][c2][r][ll];
    const float gv = gsum[rr];
    const float hv = gv / (1.f + __expf(-gv)) * us;    // silu(g)*u
    const int m  = c2 * 16 + (ll >> 4) * 4 + r;        // C/D: row=(l>>4)*4+r
    const int ii = n0 + (ll & 15);                     //      col=l&15
    hb[(size_t)m * I_DIM + ii] = f2bf(hv);
  }
}

// ---------------- packed phase2: down GEMM, split-K x4 ----------------
__global__ __launch_bounds__(512, 4) void phase2p_kernel(
    const short* __restrict__ hb,
    const int* __restrict__ dp, const float* __restrict__ dsc, const float* __restrict__ dze,
    float* __restrict__ part)
{
  __shared__ float red[8][4][4][64];   // 32 KB
  const int tile  = blockIdx.x & 255;
  const int split = blockIdx.x >> 8;
  const int n0   = tile * 16;
  const int w    = threadIdx.x >> 6;
  const int l    = threadIdx.x & 63;
  const int col  = l & 15;
  const int krow = l >> 4;
  const int n    = n0 + col;

  const int*   dpr = dp + (size_t)n * IP;
  const float* dsr = dsc + (size_t)n * NGI;
  const float* dzr = dze + (size_t)n * NGI;

  f32x4 acc[4];
#pragma unroll
  for (int c = 0; c < 4; ++c)
#pragma unroll
    for (int r = 0; r < 4; ++r) acc[c][r] = 0.f;

  const int cnt    = (w < 6) ? 11 : 10;
  const int sstart = (w < 6) ? w * 11 : 66 + (w - 6) * 10;
  const int kbase  = split * 2752 + sstart * 32;   // int-element base (for groups)
  const int wbase  = split * 344 + sstart * 4;     // packed-word base

  int gprev = -1;
  float sv = 0.f, zv = 0.f;

  int qd = dpr[wbase + krow];
#pragma unroll 1
  for (int s = 0; s < cnt; ++s) {
    const int cd = qd;
    {
      const int ns = (s + 1 < cnt) ? (s + 1) : 0;
      qd = dpr[wbase + ns * 4 + krow];
    }
    const int k0 = kbase + s * 32;
    const int g  = k0 >> 7;
    if (g != gprev) { sv = dsr[g]; zv = dzr[g] * sv; gprev = g; }
    short8 a[4];
#pragma unroll
    for (int c = 0; c < 4; ++c)
      a[c] = *(const short8*)(hb + (size_t)(c * 16 + col) * I_DIM + k0 + krow * 8);
    short8 b;
#pragma unroll
    for (int j = 0; j < 8; ++j)
      b[j] = f2bf((float)((cd >> (4 * j)) & 15) * sv - zv);
#pragma unroll
    for (int c = 0; c < 4; ++c)
      acc[c] = __builtin_amdgcn_mfma_f32_16x16x32_bf16(a[c], b, acc[c], 0, 0, 0);
  }

#pragma unroll
  for (int c = 0; c < 4; ++c)
#pragma unroll
    for (int r = 0; r < 4; ++r)
      red[w][c][r][l] = acc[c][r];
  __syncthreads();

  if (threadIdx.x < 256) {
    const int c2 = threadIdx.x >> 6;
    const int ll = threadIdx.x & 63;
    float* po = part + (size_t)split * (64 * H_DIM);
#pragma unroll
    for (int r = 0; r < 4; ++r) {
      float s = 0.f;
#pragma unroll
      for (int ww = 0; ww < 8; ++ww) s += red[ww][c2][r][ll];
      const int m  = c2 * 16 + (ll >> 4) * 4 + r;
      const int nn = n0 + (ll & 15);
      po[(size_t)m * H_DIM + nn] = s;
    }
  }
}

__global__ void reduce4_kernel(const float* __restrict__ part, float* __restrict__ out) {
  const int idx = (blockIdx.x * 256 + threadIdx.x) * 4;
  const int S = 64 * H_DIM;
  f32x4 s0 = *(const f32x4*)(part + idx);
  f32x4 s1 = *(const f32x4*)(part + S + idx);
  f32x4 s2 = *(const f32x4*)(part + 2 * S + idx);
  f32x4 s3 = *(const f32x4*)(part + 3 * S + idx);
  f32x4 r = (s0 + s1) + (s2 + s3);
  *(f32x4*)(out + idx) = r;
}

// ---------------- fallback (round-5) kernels, used if ws too small ----------------
__global__ __launch_bounds__(512, 4) void phase1f_kernel(
    const short* __restrict__ xb,
    const int* __restrict__ gq, const float* __restrict__ gsc, const float* __restrict__ gze,
    const int* __restrict__ uq, const float* __restrict__ usc, const float* __restrict__ uze,
    short* __restrict__ hb)
{
  __shared__ float red[8][4][4][64];
  const int n0   = blockIdx.x * 16;
  const int w    = threadIdx.x >> 6;
  const int l    = threadIdx.x & 63;
  const int col  = l & 15;
  const int krow = l >> 4;
  const int i    = n0 + col;
  const int*   gqr = gq + (size_t)i * H_DIM;
  const int*   uqr = uq + (size_t)i * H_DIM;
  const float* gsr = gsc + (size_t)i * NGH;
  const float* gzr = gze + (size_t)i * NGH;
  const float* usr = usc + (size_t)i * NGH;
  const float* uzr = uze + (size_t)i * NGH;
  f32x4 accG[4], accU[4];
#pragma unroll
  for (int c = 0; c < 4; ++c)
#pragma unroll
    for (int r = 0; r < 4; ++r) { accG[c][r] = 0.f; accU[c][r] = 0.f; }
  const int kw = w * 512;
  int pk = kw + krow * 8;
  i32x4 nq0 = *(const i32x4*)(gqr + pk);
  i32x4 nq1 = *(const i32x4*)(gqr + pk + 4);
  i32x4 np0 = *(const i32x4*)(uqr + pk);
  i32x4 np1 = *(const i32x4*)(uqr + pk + 4);
#pragma unroll 1
  for (int g = 0; g < 4; ++g) {
    const int gg = w * 4 + g;
    const float sg = gsr[gg], zg = gzr[gg] * sg;
    const float su = usr[gg], zu = uzr[gg] * su;
#pragma unroll
    for (int ks = 0; ks < 4; ++ks) {
      i32x4 q0 = nq0, q1 = nq1, p0 = np0, p1 = np1;
      const int klocal = g * 128 + ks * 32;
      {
        const int nk = kw + ((klocal + 32) & 511) + krow * 8;
        nq0 = *(const i32x4*)(gqr + nk);
        nq1 = *(const i32x4*)(gqr + nk + 4);
        np0 = *(const i32x4*)(uqr + nk);
        np1 = *(const i32x4*)(uqr + nk + 4);
      }
      const int koff = kw + klocal + krow * 8;
      short8 a[4];
#pragma unroll
      for (int c = 0; c < 4; ++c)
        a[c] = *(const short8*)(xb + (size_t)(c * 16 + col) * H_DIM + koff);
      short8 bg, bu;
#pragma unroll
      for (int j = 0; j < 4; ++j) {
        bg[j]     = f2bf((float)q0[j] * sg - zg);
        bg[j + 4] = f2bf((float)q1[j] * sg - zg);
        bu[j]     = f2bf((float)p0[j] * su - zu);
        bu[j + 4] = f2bf((float)p1[j] * su - zu);
      }
#pragma unroll
      for (int c = 0; c < 4; ++c) {
        accG[c] = __builtin_amdgcn_mfma_f32_16x16x32_bf16(a[c], bg, accG[c], 0, 0, 0);
        accU[c] = __builtin_amdgcn_mfma_f32_16x16x32_bf16(a[c], bu, accU[c], 0, 0, 0);
      }
    }
  }
  const int c2 = threadIdx.x >> 7;
  const int rh = (threadIdx.x >> 6) & 1;
  const int ll = threadIdx.x & 63;
#pragma unroll
  for (int c = 0; c < 4; ++c)
#pragma unroll
    for (int r = 0; r < 4; ++r)
      red[w][c][r][l] = accG[c][r];
  __syncthreads();
  float gsum[2];
#pragma unroll
  for (int rr = 0; rr < 2; ++rr) {
    const int r = rh * 2 + rr;
    float s = 0.f;
#pragma unroll
    for (int ww = 0; ww < 8; ++ww) s += red[ww][c2][r][ll];
    gsum[rr] = s;
  }
  __syncthreads();
#pragma unroll
  for (int c = 0; c < 4; ++c)
#pragma unroll
    for (int r = 0; r < 4; ++r)
      red[w][c][r][l] = accU[c][r];
  __syncthreads();
#pragma unroll
  for (int rr = 0; rr < 2; ++rr) {
    const int r = rh * 2 + rr;
    float us = 0.f;
#pragma unroll
    for (int ww = 0; ww < 8; ++ww) us += red[ww][c2][r][ll];
    const float gv = gsum[rr];
    const float hv = gv / (1.f + __expf(-gv)) * us;
    const int m  = c2 * 16 + (ll >> 4) * 4 + r;
    const int ii = n0 + (ll & 15);
    hb[(size_t)m * I_DIM + ii] = f2bf(hv);
  }
}

__global__ __launch_bounds__(512, 4) void phase2f_kernel(
    const short* __restrict__ hb,
    const int* __restrict__ dq, const float* __restrict__ dsc, const float* __restrict__ dze,
    float* __restrict__ part)
{
  __shared__ float red[8][4][4][64];
  const int tile  = blockIdx.x & 255;
  const int split = blockIdx.x >> 8;
  const int n0   = tile * 16;
  const int w    = threadIdx.x >> 6;
  const int l    = threadIdx.x & 63;
  const int col  = l & 15;
  const int krow = l >> 4;
  const int n    = n0 + col;
  const int*   dqr = dq + (size_t)n * I_DIM;
  const float* dsr = dsc + (size_t)n * NGI;
  const float* dzr = dze + (size_t)n * NGI;
  f32x4 acc[4];
#pragma unroll
  for (int c = 0; c < 4; ++c)
#pragma unroll
    for (int r = 0; r < 4; ++r) acc[c][r] = 0.f;
  const int cnt    = (w < 6) ? 11 : 10;
  const int sstart = (w < 6) ? w * 11 : 66 + (w - 6) * 10;
  const int kbase  = split * 2752 + sstart * 32;
  int gprev = -1;
  float sv = 0.f, zv = 0.f;
  int pk = kbase + krow * 8;
  i32x4 nq0 = *(const i32x4*)(dqr + pk);
  i32x4 nq1 = *(const i32x4*)(dqr + pk + 4);
#pragma unroll 1
  for (int s = 0; s < cnt; ++s) {
    i32x4 q0 = nq0, q1 = nq1;
    {
      const int ns = (s + 1 < cnt) ? (s + 1) : 0;
      const int nk = kbase + ns * 32 + krow * 8;
      nq0 = *(const i32x4*)(dqr + nk);
      nq1 = *(const i32x4*)(dqr + nk + 4);
    }
    const int k0 = kbase + s * 32;
    const int g  = k0 >> 7;
    if (g != gprev) { sv = dsr[g]; zv = dzr[g] * sv; gprev = g; }
    short8 a[4];
#pragma unroll
    for (int c = 0; c < 4; ++c)
      a[c] = *(const short8*)(hb + (size_t)(c * 16 + col) * I_DIM + k0 + krow * 8);
    short8 b;
#pragma unroll
    for (int j = 0; j < 4; ++j) {
      b[j]     = f2bf((float)q0[j] * sv - zv);
      b[j + 4] = f2bf((float)q1[j] * sv - zv);
    }
#pragma unroll
    for (int c = 0; c < 4; ++c)
      acc[c] = __builtin_amdgcn_mfma_f32_16x16x32_bf16(a[c], b, acc[c], 0, 0, 0);
  }
#pragma unroll
  for (int c = 0; c < 4; ++c)
#pragma unroll
    for (int r = 0; r < 4; ++r)
      red[w][c][r][l] = acc[c][r];
  __syncthreads();
  if (threadIdx.x < 256) {
    const int c2 = threadIdx.x >> 6;
    const int ll = threadIdx.x & 63;
    float* po = part + (size_t)split * (64 * H_DIM);
#pragma unroll
    for (int r = 0; r < 4; ++r) {
      float s = 0.f;
#pragma unroll
      for (int ww = 0; ww < 8; ++ww) s += red[ww][c2][r][ll];
      const int m  = c2 * 16 + (ll >> 4) * 4 + r;
      const int nn = n0 + (ll & 15);
      po[(size_t)m * H_DIM + nn] = s;
    }
  }
}

extern "C" void kernel_launch(void* const* d_in, const int* in_sizes, int n_in,
                              void* d_out, int out_size, void* d_ws, size_t ws_size,
                              hipStream_t stream) {
  const float* x  = (const float*)d_in[0];
  const int*   gq = (const int*)d_in[1];
  const float* gs = (const float*)d_in[2];
  const float* gz = (const float*)d_in[3];
  const int*   uq = (const int*)d_in[4];
  const float* us = (const float*)d_in[5];
  const float* uz = (const float*)d_in[6];
  const int*   dq = (const int*)d_in[7];
  const float* ds = (const float*)d_in[8];
  const float* dz = (const float*)d_in[9];
  float* out = (float*)d_out;

  const size_t XB   = (size_t)64 * H_DIM * 2;          // 512 KB
  const size_t HB   = (size_t)64 * I_DIM * 2;          // 1.376 MB
  const size_t PART = (size_t)4 * 64 * H_DIM * 4;      // 4 MB
  const size_t NW   = (size_t)I_DIM * HP;              // 5,636,096 packed words each
  const size_t PK   = NW * 4;                          // 22.5 MB each

  short* xb   = (short*)d_ws;
  short* hb   = (short*)((char*)d_ws + XB);
  float* part = (float*)((char*)d_ws + XB + HB);
  int*   gp   = (int*)((char*)d_ws + XB + HB + PART);
  int*   upk  = (int*)((char*)d_ws + XB + HB + PART + PK);
  int*   dpk  = (int*)((char*)d_ws + XB + HB + PART + 2 * PK);

  xcvt_kernel<<<(64 * H_DIM) / 1024, 256, 0, stream>>>(x, xb);

  if (ws_size >= XB + HB + PART + 3 * PK) {
    const int pblk = (int)(NW / 256);   // 22016, exact
    pack_kernel<<<pblk, 256, 0, stream>>>(gq, gp);
    pack_kernel<<<pblk, 256, 0, stream>>>(uq, upk);
    phase1p_kernel<<<I_DIM / 16, 512, 0, stream>>>(xb, gp, gs, gz, upk, us, uz, hb);
    pack_kernel<<<pblk, 256, 0, stream>>>(dq, dpk);
    phase2p_kernel<<<(H_DIM / 16) * 4, 512, 0, stream>>>(hb, dpk, ds, dz, part);
  } else {
    phase1f_kernel<<<I_DIM / 16, 512, 0, stream>>>(xb, gq, gs, gz, uq, us, uz, hb);
    phase2f_kernel<<<(H_DIM / 16) * 4, 512, 0, stream>>>(hb, dq, ds, dz, part);
  }
  reduce4_kernel<<<(64 * H_DIM) / 1024, 256, 0, stream>>>(part, out);
}

// Round 9
// 242.964 us; speedup vs baseline: 1.0148x; 1.0148x over previous
//
#include <hip/hip_runtime.h>
#include <hip/hip_bf16.h>
#include <stdint.h>

#define H_DIM 4096
#define I_DIM 11008
#define NGH   32    // H/128 groups (gate/up)
#define NGI   86    // I/128 groups (down)
#define HP    (H_DIM/8)   // 512 packed words per gate/up row
#define IP    (I_DIM/8)   // 1376 packed words per down row
#define NWV   5636096     // packed words per matrix (same for all three)

typedef __attribute__((ext_vector_type(8))) short short8;
typedef __attribute__((ext_vector_type(4))) short s16x4;
typedef __attribute__((ext_vector_type(4))) float f32x4;
typedef __attribute__((ext_vector_type(4))) int   i32x4;

static __device__ __forceinline__ short f2bf(float f) {
  union { __hip_bfloat16 b; short s; } u;
  u.b = __float2bfloat16(f);
  return u.s;
}

__global__ void xcvt_kernel(const float* __restrict__ x, short* __restrict__ xb) {
  int i = (blockIdx.x * 256 + threadIdx.x) * 4;
  f32x4 v = *(const f32x4*)(x + i);
  s16x4 o;
  o[0] = f2bf(v[0]); o[1] = f2bf(v[1]); o[2] = f2bf(v[2]); o[3] = f2bf(v[3]);
  *(s16x4*)(xb + i) = o;
}

// ---- pack3: all three qweight matrices -> nibble-packed, one dense stream ----
__global__ __launch_bounds__(256) void pack3_kernel(
    const int* __restrict__ gq, const int* __restrict__ uq, const int* __restrict__ dq,
    int* __restrict__ dst) {
  const int m = blockIdx.x / 22016;          // 0=gate 1=up 2=down (22016*256=NWV)
  const int* src = (m == 0) ? gq : (m == 1) ? uq : dq;
  const size_t o = (size_t)(blockIdx.x - m * 22016) * 256 + threadIdx.x;
  const int* s = src + o * 8;
  i32x4 a = *(const i32x4*)s;
  i32x4 b = *(const i32x4*)(s + 4);
  int p = (a[0] & 15)         | ((a[1] & 15) << 4)  | ((a[2] & 15) << 8)  | ((a[3] & 15) << 12)
        | ((b[0] & 15) << 16) | ((b[1] & 15) << 20) | ((b[2] & 15) << 24) | ((b[3] & 15) << 28);
  dst[(size_t)m * NWV + o] = p;
}

// ---------------- packed phase1: gate+up GEMM + SwiGLU ----------------
// Grid: I/16 blocks x 512 thr (8 waves). Wave w: K-seg of 512 ints (64 words).
// Register-double-buffered a-frags + packed words (counted-vmcnt pipeline).
__global__ __launch_bounds__(512, 4) void phase1p_kernel(
    const short* __restrict__ xb,
    const int* __restrict__ gp, const float* __restrict__ gsc, const float* __restrict__ gze,
    const int* __restrict__ up, const float* __restrict__ usc, const float* __restrict__ uze,
    short* __restrict__ hb)
{
  __shared__ float red[8][4][4][64];   // 32 KB, reused for G then U
  const int n0   = blockIdx.x * 16;
  const int w    = threadIdx.x >> 6;
  const int l    = threadIdx.x & 63;
  const int col  = l & 15;
  const int krow = l >> 4;
  const int i    = n0 + col;

  const int*   gpr = gp + (size_t)i * HP;
  const int*   upr = up + (size_t)i * HP;

  // hoist all 4 groups' scale/zero out of the K-loop (no mid-loop vmem)
  float sgv[4], zgv[4], suv[4], zuv[4];
#pragma unroll
  for (int g = 0; g < 4; ++g) {
    const int gg = w * 4 + g;
    sgv[g] = gsc[(size_t)i * NGH + gg];
    zgv[g] = gze[(size_t)i * NGH + gg] * sgv[g];
    suv[g] = usc[(size_t)i * NGH + gg];
    zuv[g] = uze[(size_t)i * NGH + gg] * suv[g];
  }

  f32x4 accG[4], accU[4];
#pragma unroll
  for (int c = 0; c < 4; ++c)
#pragma unroll
    for (int r = 0; r < 4; ++r) { accG[c][r] = 0.f; accU[c][r] = 0.f; }

  const int wb = w * 64;               // packed word base
  const int ks0 = w * 512 + krow * 8;  // int-k base for a-loads

  // preload t=0 into buffer A
  int qgA = gpr[wb + krow], quA = upr[wb + krow];
  int qgB, quB;
  short8 aA[4], aB[4];
#pragma unroll
  for (int c = 0; c < 4; ++c)
    aA[c] = *(const short8*)(xb + (size_t)(c * 16 + col) * H_DIM + ks0);

#pragma unroll
  for (int u = 0; u < 8; ++u) {
    const int t1 = 2 * u + 1;
    const int t2 = (2 * u + 2) & 15;   // wraps to 0 on last (harmless)
    const int g  = u >> 1;             // group of both t0 and t1 (static)
    // issue t1 -> B
    qgB = gpr[wb + 4 * t1 + krow];
    quB = upr[wb + 4 * t1 + krow];
#pragma unroll
    for (int c = 0; c < 4; ++c)
      aB[c] = *(const short8*)(xb + (size_t)(c * 16 + col) * H_DIM + ks0 + t1 * 32);
    // compute t0 from A (waits only 6-deep-old loads)
    {
      short8 bg, bu;
#pragma unroll
      for (int j = 0; j < 8; ++j) {
        bg[j] = f2bf((float)((qgA >> (4 * j)) & 15) * sgv[g] - zgv[g]);
        bu[j] = f2bf((float)((quA >> (4 * j)) & 15) * suv[g] - zuv[g]);
      }
#pragma unroll
      for (int c = 0; c < 4; ++c) {
        accG[c] = __builtin_amdgcn_mfma_f32_16x16x32_bf16(aA[c], bg, accG[c], 0, 0, 0);
        accU[c] = __builtin_amdgcn_mfma_f32_16x16x32_bf16(aA[c], bu, accU[c], 0, 0, 0);
      }
    }
    // issue t2 -> A
    qgA = gpr[wb + 4 * t2 + krow];
    quA = upr[wb + 4 * t2 + krow];
#pragma unroll
    for (int c = 0; c < 4; ++c)
      aA[c] = *(const short8*)(xb + (size_t)(c * 16 + col) * H_DIM + ks0 + t2 * 32);
    // compute t1 from B
    {
      short8 bg, bu;
#pragma unroll
      for (int j = 0; j < 8; ++j) {
        bg[j] = f2bf((float)((qgB >> (4 * j)) & 15) * sgv[g] - zgv[g]);
        bu[j] = f2bf((float)((quB >> (4 * j)) & 15) * suv[g] - zuv[g]);
      }
#pragma unroll
      for (int c = 0; c < 4; ++c) {
        accG[c] = __builtin_amdgcn_mfma_f32_16x16x32_bf16(aB[c], bg, accG[c], 0, 0, 0);
        accU[c] = __builtin_amdgcn_mfma_f32_16x16x32_bf16(aB[c], bu, accU[c], 0, 0, 0);
      }
    }
  }

  const int c2 = threadIdx.x >> 7;
  const int rh = (threadIdx.x >> 6) & 1;
  const int ll = threadIdx.x & 63;

#pragma unroll
  for (int c = 0; c < 4; ++c)
#pragma unroll
    for (int r = 0; r < 4; ++r)
      red[w][c][r][l] = accG[c][r];
  __syncthreads();
  float gsum[2];
#pragma unroll
  for (int rr = 0; rr < 2; ++rr) {
    const int r = rh * 2 + rr;
    float s = 0.f;
#pragma unroll
    for (int ww = 0; ww < 8; ++ww) s += red[ww][c2][r][ll];
    gsum[rr] = s;
  }
  __syncthreads();

#pragma unroll
  for (int c = 0; c < 4; ++c)
#pragma unroll
    for (int r = 0; r < 4; ++r)
      red[w][c][r][l] = accU[c][r];
  __syncthreads();
#pragma unroll
  for (int rr = 0; rr < 2; ++rr) {
    const int r = rh * 2 + rr;
    float us = 0.f;
#pragma unroll
    for (int ww = 0; ww < 8; ++ww) us += red[ww][c2][r][ll];
    const float gv = gsum[rr];
    const float hv = gv / (1.f + __expf(-gv)) * us;    // silu(g)*u
    const int m  = c2 * 16 + (ll >> 4) * 4 + r;        // C/D: row=(l>>4)*4+r
    const int ii = n0 + (ll & 15);                     //      col=l&15
    hb[(size_t)m * I_DIM + ii] = f2bf(hv);
  }
}

// ---------------- packed phase2: down GEMM, split-K x4 ----------------
__global__ __launch_bounds__(512, 4) void phase2p_kernel(
    const short* __restrict__ hb,
    const int* __restrict__ dp, const float* __restrict__ dsc, const float* __restrict__ dze,
    float* __restrict__ part)
{
  __shared__ float red[8][4][4][64];   // 32 KB
  const int tile  = blockIdx.x & 255;
  const int split = blockIdx.x >> 8;
  const int n0   = tile * 16;
  const int w    = threadIdx.x >> 6;
  const int l    = threadIdx.x & 63;
  const int col  = l & 15;
  const int krow = l >> 4;
  const int n    = n0 + col;

  const int* dpr = dp + (size_t)n * IP;

  f32x4 acc[4];
#pragma unroll
  for (int c = 0; c < 4; ++c)
#pragma unroll
    for (int r = 0; r < 4; ++r) acc[c][r] = 0.f;

  const int cnt    = (w < 6) ? 11 : 10;
  const int sstart = (w < 6) ? w * 11 : 66 + (w - 6) * 10;
  const int kbase  = split * 2752 + sstart * 32;   // int-element base
  const int wbase  = split * 344 + sstart * 4;     // packed-word base

  // preload the <=4 groups this wave can touch
  const int g0 = kbase >> 7;
  float s0 = dsc[(size_t)n * NGI + g0];
  float s1 = dsc[(size_t)n * NGI + min(g0 + 1, NGI - 1)];
  float s2 = dsc[(size_t)n * NGI + min(g0 + 2, NGI - 1)];
  float s3 = dsc[(size_t)n * NGI + min(g0 + 3, NGI - 1)];
  float z0 = dze[(size_t)n * NGI + g0] * s0;
  float z1 = dze[(size_t)n * NGI + min(g0 + 1, NGI - 1)] * s1;
  float z2 = dze[(size_t)n * NGI + min(g0 + 2, NGI - 1)] * s2;
  float z3 = dze[(size_t)n * NGI + min(g0 + 3, NGI - 1)] * s3;

  int qdA = dpr[wbase + krow], qdB;
  short8 aA[4], aB[4];
#pragma unroll
  for (int c = 0; c < 4; ++c)
    aA[c] = *(const short8*)(hb + (size_t)(c * 16 + col) * I_DIM + kbase + krow * 8);

  const int nh = cnt >> 1;
#pragma unroll 1
  for (int u = 0; u < nh; ++u) {
    const int t0 = 2 * u, t1 = 2 * u + 1;
    const int t2 = (t1 + 1 < cnt) ? (t1 + 1) : 0;
    // issue t1 -> B
    qdB = dpr[wbase + 4 * t1 + krow];
#pragma unroll
    for (int c = 0; c < 4; ++c)
      aB[c] = *(const short8*)(hb + (size_t)(c * 16 + col) * I_DIM + kbase + t1 * 32 + krow * 8);
    // compute t0 from A
    {
      const int gi = ((kbase + t0 * 32) >> 7) - g0;
      const float sv = gi == 0 ? s0 : gi == 1 ? s1 : gi == 2 ? s2 : s3;
      const float zv = gi == 0 ? z0 : gi == 1 ? z1 : gi == 2 ? z2 : z3;
      short8 b;
#pragma unroll
      for (int j = 0; j < 8; ++j)
        b[j] = f2bf((float)((qdA >> (4 * j)) & 15) * sv - zv);
#pragma unroll
      for (int c = 0; c < 4; ++c)
        acc[c] = __builtin_amdgcn_mfma_f32_16x16x32_bf16(aA[c], b, acc[c], 0, 0, 0);
    }
    // issue t2 -> A
    qdA = dpr[wbase + 4 * t2 + krow];
#pragma unroll
    for (int c = 0; c < 4; ++c)
      aA[c] = *(const short8*)(hb + (size_t)(c * 16 + col) * I_DIM + kbase + t2 * 32 + krow * 8);
    // compute t1 from B
    {
      const int gi = ((kbase + t1 * 32) >> 7) - g0;
      const float sv = gi == 0 ? s0 : gi == 1 ? s1 : gi == 2 ? s2 : s3;
      const float zv = gi == 0 ? z0 : gi == 1 ? z1 : gi == 2 ? z2 : z3;
      short8 b;
#pragma unroll
      for (int j = 0; j < 8; ++j)
        b[j] = f2bf((float)((qdB >> (4 * j)) & 15) * sv - zv);
#pragma unroll
      for (int c = 0; c < 4; ++c)
        acc[c] = __builtin_amdgcn_mfma_f32_16x16x32_bf16(aB[c], b, acc[c], 0, 0, 0);
    }
  }
  if (cnt & 1) {   // tail t = cnt-1 (already loaded in A by last iteration)
    const int t0 = cnt - 1;
    const int gi = ((kbase + t0 * 32) >> 7) - g0;
    const float sv = gi == 0 ? s0 : gi == 1 ? s1 : gi == 2 ? s2 : s3;
    const float zv = gi == 0 ? z0 : gi == 1 ? z1 : gi == 2 ? z2 : z3;
    short8 b;
#pragma unroll
    for (int j = 0; j < 8; ++j)
      b[j] = f2bf((float)((qdA >> (4 * j)) & 15) * sv - zv);
#pragma unroll
    for (int c = 0; c < 4; ++c)
      acc[c] = __builtin_amdgcn_mfma_f32_16x16x32_bf16(aA[c], b, acc[c], 0, 0, 0);
  }

#pragma unroll
  for (int c = 0; c < 4; ++c)
#pragma unroll
    for (int r = 0; r < 4; ++r)
      red[w][c][r][l] = acc[c][r];
  __syncthreads();

  if (threadIdx.x < 256) {
    const int c2 = threadIdx.x >> 6;
    const int ll = threadIdx.x & 63;
    float* po = part + (size_t)split * (64 * H_DIM);
#pragma unroll
    for (int r = 0; r < 4; ++r) {
      float s = 0.f;
#pragma unroll
      for (int ww = 0; ww < 8; ++ww) s += red[ww][c2][r][ll];
      const int m  = c2 * 16 + (ll >> 4) * 4 + r;
      const int nn = n0 + (ll & 15);
      po[(size_t)m * H_DIM + nn] = s;
    }
  }
}

__global__ void reduce4_kernel(const float* __restrict__ part, float* __restrict__ out) {
  const int idx = (blockIdx.x * 256 + threadIdx.x) * 4;
  const int S = 64 * H_DIM;
  f32x4 s0 = *(const f32x4*)(part + idx);
  f32x4 s1 = *(const f32x4*)(part + S + idx);
  f32x4 s2 = *(const f32x4*)(part + 2 * S + idx);
  f32x4 s3 = *(const f32x4*)(part + 3 * S + idx);
  f32x4 r = (s0 + s1) + (s2 + s3);
  *(f32x4*)(out + idx) = r;
}

// ---------------- fallback (round-5) kernels, used if ws too small ----------------
__global__ __launch_bounds__(512, 4) void phase1f_kernel(
    const short* __restrict__ xb,
    const int* __restrict__ gq, const float* __restrict__ gsc, const float* __restrict__ gze,
    const int* __restrict__ uq, const float* __restrict__ usc, const float* __restrict__ uze,
    short* __restrict__ hb)
{
  __shared__ float red[8][4][4][64];
  const int n0   = blockIdx.x * 16;
  const int w    = threadIdx.x >> 6;
  const int l    = threadIdx.x & 63;
  const int col  = l & 15;
  const int krow = l >> 4;
  const int i    = n0 + col;
  const int*   gqr = gq + (size_t)i * H_DIM;
  const int*   uqr = uq + (size_t)i * H_DIM;
  const float* gsr = gsc + (size_t)i * NGH;
  const float* gzr = gze + (size_t)i * NGH;
  const float* usr = usc + (size_t)i * NGH;
  const float* uzr = uze + (size_t)i * NGH;
  f32x4 accG[4], accU[4];
#pragma unroll
  for (int c = 0; c < 4; ++c)
#pragma unroll
    for (int r = 0; r < 4; ++r) { accG[c][r] = 0.f; accU[c][r] = 0.f; }
  const int kw = w * 512;
  int pk = kw + krow * 8;
  i32x4 nq0 = *(const i32x4*)(gqr + pk);
  i32x4 nq1 = *(const i32x4*)(gqr + pk + 4);
  i32x4 np0 = *(const i32x4*)(uqr + pk);
  i32x4 np1 = *(const i32x4*)(uqr + pk + 4);
#pragma unroll 1
  for (int g = 0; g < 4; ++g) {
    const int gg = w * 4 + g;
    const float sg = gsr[gg], zg = gzr[gg] * sg;
    const float su = usr[gg], zu = uzr[gg] * su;
#pragma unroll
    for (int ks = 0; ks < 4; ++ks) {
      i32x4 q0 = nq0, q1 = nq1, p0 = np0, p1 = np1;
      const int klocal = g * 128 + ks * 32;
      {
        const int nk = kw + ((klocal + 32) & 511) + krow * 8;
        nq0 = *(const i32x4*)(gqr + nk);
        nq1 = *(const i32x4*)(gqr + nk + 4);
        np0 = *(const i32x4*)(uqr + nk);
        np1 = *(const i32x4*)(uqr + nk + 4);
      }
      const int koff = kw + klocal + krow * 8;
      short8 a[4];
#pragma unroll
      for (int c = 0; c < 4; ++c)
        a[c] = *(const short8*)(xb + (size_t)(c * 16 + col) * H_DIM + koff);
      short8 bg, bu;
#pragma unroll
      for (int j = 0; j < 4; ++j) {
        bg[j]     = f2bf((float)q0[j] * sg - zg);
        bg[j + 4] = f2bf((float)q1[j] * sg - zg);
        bu[j]     = f2bf((float)p0[j] * su - zu);
        bu[j + 4] = f2bf((float)p1[j] * su - zu);
      }
#pragma unroll
      for (int c = 0; c < 4; ++c) {
        accG[c] = __builtin_amdgcn_mfma_f32_16x16x32_bf16(a[c], bg, accG[c], 0, 0, 0);
        accU[c] = __builtin_amdgcn_mfma_f32_16x16x32_bf16(a[c], bu, accU[c], 0, 0, 0);
      }
    }
  }
  const int c2 = threadIdx.x >> 7;
  const int rh = (threadIdx.x >> 6) & 1;
  const int ll = threadIdx.x & 63;
#pragma unroll
  for (int c = 0; c < 4; ++c)
#pragma unroll
    for (int r = 0; r < 4; ++r)
      red[w][c][r][l] = accG[c][r];
  __syncthreads();
  float gsum[2];
#pragma unroll
  for (int rr = 0; rr < 2; ++rr) {
    const int r = rh * 2 + rr;
    float s = 0.f;
#pragma unroll
    for (int ww = 0; ww < 8; ++ww) s += red[ww][c2][r][ll];
    gsum[rr] = s;
  }
  __syncthreads();
#pragma unroll
  for (int c = 0; c < 4; ++c)
#pragma unroll
    for (int r = 0; r < 4; ++r)
      red[w][c][r][l] = accU[c][r];
  __syncthreads();
#pragma unroll
  for (int rr = 0; rr < 2; ++rr) {
    const int r = rh * 2 + rr;
    float us = 0.f;
#pragma unroll
    for (int ww = 0; ww < 8; ++ww) us += red[ww][c2][r][ll];
    const float gv = gsum[rr];
    const float hv = gv / (1.f + __expf(-gv)) * us;
    const int m  = c2 * 16 + (ll >> 4) * 4 + r;
    const int ii = n0 + (ll & 15);
    hb[(size_t)m * I_DIM + ii] = f2bf(hv);
  }
}

__global__ __launch_bounds__(512, 4) void phase2f_kernel(
    const short* __restrict__ hb,
    const int* __restrict__ dq, const float* __restrict__ dsc, const float* __restrict__ dze,
    float* __restrict__ part)
{
  __shared__ float red[8][4][4][64];
  const int tile  = blockIdx.x & 255;
  const int split = blockIdx.x >> 8;
  const int n0   = tile * 16;
  const int w    = threadIdx.x >> 6;
  const int l    = threadIdx.x & 63;
  const int col  = l & 15;
  const int krow = l >> 4;
  const int n    = n0 + col;
  const int*   dqr = dq + (size_t)n * I_DIM;
  const float* dsr = dsc + (size_t)n * NGI;
  const float* dzr = dze + (size_t)n * NGI;
  f32x4 acc[4];
#pragma unroll
  for (int c = 0; c < 4; ++c)
#pragma unroll
    for (int r = 0; r < 4; ++r) acc[c][r] = 0.f;
  const int cnt    = (w < 6) ? 11 : 10;
  const int sstart = (w < 6) ? w * 11 : 66 + (w - 6) * 10;
  const int kbase  = split * 2752 + sstart * 32;
  int gprev = -1;
  float sv = 0.f, zv = 0.f;
  int pk = kbase + krow * 8;
  i32x4 nq0 = *(const i32x4*)(dqr + pk);
  i32x4 nq1 = *(const i32x4*)(dqr + pk + 4);
#pragma unroll 1
  for (int s = 0; s < cnt; ++s) {
    i32x4 q0 = nq0, q1 = nq1;
    {
      const int ns = (s + 1 < cnt) ? (s + 1) : 0;
      const int nk = kbase + ns * 32 + krow * 8;
      nq0 = *(const i32x4*)(dqr + nk);
      nq1 = *(const i32x4*)(dqr + nk + 4);
    }
    const int k0 = kbase + s * 32;
    const int g  = k0 >> 7;
    if (g != gprev) { sv = dsr[g]; zv = dzr[g] * sv; gprev = g; }
    short8 a[4];
#pragma unroll
    for (int c = 0; c < 4; ++c)
      a[c] = *(const short8*)(hb + (size_t)(c * 16 + col) * I_DIM + k0 + krow * 8);
    short8 b;
#pragma unroll
    for (int j = 0; j < 4; ++j) {
      b[j]     = f2bf((float)q0[j] * sv - zv);
      b[j + 4] = f2bf((float)q1[j] * sv - zv);
    }
#pragma unroll
    for (int c = 0; c < 4; ++c)
      acc[c] = __builtin_amdgcn_mfma_f32_16x16x32_bf16(a[c], b, acc[c], 0, 0, 0);
  }
#pragma unroll
  for (int c = 0; c < 4; ++c)
#pragma unroll
    for (int r = 0; r < 4; ++r)
      red[w][c][r][l] = acc[c][r];
  __syncthreads();
  if (threadIdx.x < 256) {
    const int c2 = threadIdx.x >> 6;
    const int ll = threadIdx.x & 63;
    float* po = part + (size_t)split * (64 * H_DIM);
#pragma unroll
    for (int r = 0; r < 4; ++r) {
      float s = 0.f;
#pragma unroll
      for (int ww = 0; ww < 8; ++ww) s += red[ww][c2][r][ll];
      const int m  = c2 * 16 + (ll >> 4) * 4 + r;
      const int nn = n0 + (ll & 15);
      po[(size_t)m * H_DIM + nn] = s;
    }
  }
}

extern "C" void kernel_launch(void* const* d_in, const int* in_sizes, int n_in,
                              void* d_out, int out_size, void* d_ws, size_t ws_size,
                              hipStream_t stream) {
  const float* x  = (const float*)d_in[0];
  const int*   gq = (const int*)d_in[1];
  const float* gs = (const float*)d_in[2];
  const float* gz = (const float*)d_in[3];
  const int*   uq = (const int*)d_in[4];
  const float* us = (const float*)d_in[5];
  const float* uz = (const float*)d_in[6];
  const int*   dq = (const int*)d_in[7];
  const float* ds = (const float*)d_in[8];
  const float* dz = (const float*)d_in[9];
  float* out = (float*)d_out;

  const size_t XB   = (size_t)64 * H_DIM * 2;          // 512 KB
  const size_t HB   = (size_t)64 * I_DIM * 2;          // 1.376 MB
  const size_t PART = (size_t)4 * 64 * H_DIM * 4;      // 4 MB
  const size_t PK   = (size_t)NWV * 4;                 // 22.5 MB each

  short* xb   = (short*)d_ws;
  short* hb   = (short*)((char*)d_ws + XB);
  float* part = (float*)((char*)d_ws + XB + HB);
  int*   pk   = (int*)((char*)d_ws + XB + HB + PART);  // [gate | up | down]
  int*   gp   = pk;
  int*   upk  = pk + NWV;
  int*   dpk  = pk + 2 * (size_t)NWV;

  xcvt_kernel<<<(64 * H_DIM) / 1024, 256, 0, stream>>>(x, xb);

  if (ws_size >= XB + HB + PART + 3 * PK) {
    pack3_kernel<<<3 * 22016, 256, 0, stream>>>(gq, uq, dq, pk);
    phase1p_kernel<<<I_DIM / 16, 512, 0, stream>>>(xb, gp, gs, gz, upk, us, uz, hb);
    phase2p_kernel<<<(H_DIM / 16) * 4, 512, 0, stream>>>(hb, dpk, ds, dz, part);
  } else {
    phase1f_kernel<<<I_DIM / 16, 512, 0, stream>>>(xb, gq, gs, gz, uq, us, uz, hb);
    phase2f_kernel<<<(H_DIM / 16) * 4, 512, 0, stream>>>(hb, dq, ds, dz, part);
  }
  reduce4_kernel<<<(64 * H_DIM) / 1024, 256, 0, stream>>>(part, out);
}

// Round 10
// 221.234 us; speedup vs baseline: 1.1144x; 1.0982x over previous
//
#include <hip/hip_runtime.h>
#include <hip/hip_bf16.h>
#include <stdint.h>

#define H_DIM 4096
#define I_DIM 11008
#define NGH   32          // H/128 groups (gate/up)
#define NGI   86          // I/128 groups (down)
#define KWH   512         // packed words per gate/up row (H/8)
#define KWI   1376        // packed words per down row (I/8)
#define NWV   5636096     // packed words per matrix (I*H/8, same all three)

typedef __attribute__((ext_vector_type(8))) short short8;
typedef __attribute__((ext_vector_type(4))) short s16x4;
typedef __attribute__((ext_vector_type(4))) float f32x4;
typedef __attribute__((ext_vector_type(4))) int   i32x4;

static __device__ __forceinline__ short f2bf(float f) {
  union { __hip_bfloat16 b; short s; } u;
  u.b = __float2bfloat16(f);
  return u.s;
}

__global__ void xcvt_kernel(const float* __restrict__ x, short* __restrict__ xb) {
  int i = (blockIdx.x * 256 + threadIdx.x) * 4;
  f32x4 v = *(const f32x4*)(x + i);
  s16x4 o;
  o[0] = f2bf(v[0]); o[1] = f2bf(v[1]); o[2] = f2bf(v[2]); o[3] = f2bf(v[3]);
  *(s16x4*)(xb + i) = o;
}

// ---- packt: nibble-pack + TRANSPOSE to fragment order pkT[rt][kw][ri] ----
// Tile = 16 rows x 256 ints. Reads: 16 thr/row x int4 = dense 16 lines/instr.
// Writes: 512 consecutive dwords (2 KB) per block.
__global__ __launch_bounds__(256) void packt_kernel(
    const int* __restrict__ gq, const int* __restrict__ uq, const int* __restrict__ dq,
    int* __restrict__ pkt) {
  __shared__ unsigned short sb[16][72];   // stride 72 us = 36 dw (%32=4): low conflicts
  int bid = blockIdx.x;
  const int* src; int RL, KW; size_t obase; int rt, ct;
  if (bid < 11008) {                       // gate: 688 rt x 16 ct
    src = gq; RL = H_DIM; KW = KWH; obase = 0;
    rt = bid >> 4; ct = bid & 15;
  } else if (bid < 22016) {                // up
    src = uq; RL = H_DIM; KW = KWH; obase = (size_t)NWV;
    bid -= 11008; rt = bid >> 4; ct = bid & 15;
  } else {                                 // down: 256 rt x 43 ct
    src = dq; RL = I_DIM; KW = KWI; obase = 2 * (size_t)NWV;
    bid -= 22016; rt = bid / 43; ct = bid - rt * 43;
  }
  const int t = threadIdx.x;
  const int rowl = t >> 4, j = t & 15;
  const int* rp = src + (size_t)(rt * 16 + rowl) * RL + ct * 256;
#pragma unroll
  for (int p = 0; p < 4; ++p) {
    i32x4 v = *(const i32x4*)(rp + p * 64 + j * 4);
    sb[rowl][p * 16 + j] = (unsigned short)((v[0] & 15) | ((v[1] & 15) << 4)
                        | ((v[2] & 15) << 8) | ((v[3] & 15) << 12));
  }
  __syncthreads();
  int* dst = pkt + obase + ((size_t)rt * KW + ct * 32) * 16;
#pragma unroll
  for (int p = 0; p < 2; ++p) {
    const int wi = t + p * 256;
    const int kwl = wi >> 4, ri = wi & 15;
    dst[wi] = (int)sb[ri][2 * kwl] | ((int)sb[ri][2 * kwl + 1] << 16);
  }
}

// ---------------- phase1: gate+up GEMM + SwiGLU (transposed-packed) ----------
// Grid: 688 blocks x 512 thr (8 waves). Wave w: K-seg of 512 ints (64 words).
// B-load: one dword/lane, 64 consecutive dwords per instr (dense 256 B).
__global__ __launch_bounds__(512, 4) void phase1p_kernel(
    const short* __restrict__ xb, const int* __restrict__ pkt,
    const float* __restrict__ gsc, const float* __restrict__ gze,
    const float* __restrict__ usc, const float* __restrict__ uze,
    short* __restrict__ hb)
{
  __shared__ float red[8][4][4][64];   // 32 KB, reused for G then U
  const int rt   = blockIdx.x;
  const int n0   = rt * 16;
  const int w    = threadIdx.x >> 6;
  const int l    = threadIdx.x & 63;
  const int col  = l & 15;
  const int krow = l >> 4;
  const int i    = n0 + col;

  // fragment-ordered weight bases (lane-invariant part + col)
  const int* gB = pkt + (size_t)rt * (KWH * 16) + col;
  const int* uB = pkt + (size_t)NWV + (size_t)rt * (KWH * 16) + col;

  // hoist all 4 groups' scale/zero out of the K-loop
  float sgv[4], zgv[4], suv[4], zuv[4];
#pragma unroll
  for (int g = 0; g < 4; ++g) {
    const int gg = w * 4 + g;
    sgv[g] = gsc[(size_t)i * NGH + gg];
    zgv[g] = gze[(size_t)i * NGH + gg] * sgv[g];
    suv[g] = usc[(size_t)i * NGH + gg];
    zuv[g] = uze[(size_t)i * NGH + gg] * suv[g];
  }

  f32x4 accG[4], accU[4];
#pragma unroll
  for (int c = 0; c < 4; ++c)
#pragma unroll
    for (int r = 0; r < 4; ++r) { accG[c][r] = 0.f; accU[c][r] = 0.f; }

  const int wb  = w * 64;              // packed word base of this wave's K-seg
  const int ks0 = w * 512 + krow * 8;  // int-k base for a-loads

  // 2-deep register double buffer
  int qgA = gB[(wb + krow) * 16], quA = uB[(wb + krow) * 16];
  int qgB_, quB_;
  short8 aA[4], aB[4];
#pragma unroll
  for (int c = 0; c < 4; ++c)
    aA[c] = *(const short8*)(xb + (size_t)(c * 16 + col) * H_DIM + ks0);

#pragma unroll
  for (int u = 0; u < 8; ++u) {
    const int t1 = 2 * u + 1;
    const int t2 = (2 * u + 2) & 15;   // wraps to 0 on last (harmless)
    const int g  = u >> 1;
    // issue t1 -> B
    qgB_ = gB[(wb + 4 * t1 + krow) * 16];
    quB_ = uB[(wb + 4 * t1 + krow) * 16];
#pragma unroll
    for (int c = 0; c < 4; ++c)
      aB[c] = *(const short8*)(xb + (size_t)(c * 16 + col) * H_DIM + ks0 + t1 * 32);
    // compute t0 from A
    {
      short8 bg, bu;
#pragma unroll
      for (int j = 0; j < 8; ++j) {
        bg[j] = f2bf((float)((qgA >> (4 * j)) & 15) * sgv[g] - zgv[g]);
        bu[j] = f2bf((float)((quA >> (4 * j)) & 15) * suv[g] - zuv[g]);
      }
#pragma unroll
      for (int c = 0; c < 4; ++c) {
        accG[c] = __builtin_amdgcn_mfma_f32_16x16x32_bf16(aA[c], bg, accG[c], 0, 0, 0);
        accU[c] = __builtin_amdgcn_mfma_f32_16x16x32_bf16(aA[c], bu, accU[c], 0, 0, 0);
      }
    }
    // issue t2 -> A
    qgA = gB[(wb + 4 * t2 + krow) * 16];
    quA = uB[(wb + 4 * t2 + krow) * 16];
#pragma unroll
    for (int c = 0; c < 4; ++c)
      aA[c] = *(const short8*)(xb + (size_t)(c * 16 + col) * H_DIM + ks0 + t2 * 32);
    // compute t1 from B
    {
      short8 bg, bu;
#pragma unroll
      for (int j = 0; j < 8; ++j) {
        bg[j] = f2bf((float)((qgB_ >> (4 * j)) & 15) * sgv[g] - zgv[g]);
        bu[j] = f2bf((float)((quB_ >> (4 * j)) & 15) * suv[g] - zuv[g]);
      }
#pragma unroll
      for (int c = 0; c < 4; ++c) {
        accG[c] = __builtin_amdgcn_mfma_f32_16x16x32_bf16(aB[c], bg, accG[c], 0, 0, 0);
        accU[c] = __builtin_amdgcn_mfma_f32_16x16x32_bf16(aB[c], bu, accU[c], 0, 0, 0);
      }
    }
  }

  const int c2 = threadIdx.x >> 7;
  const int rh = (threadIdx.x >> 6) & 1;
  const int ll = threadIdx.x & 63;

#pragma unroll
  for (int c = 0; c < 4; ++c)
#pragma unroll
    for (int r = 0; r < 4; ++r)
      red[w][c][r][l] = accG[c][r];
  __syncthreads();
  float gsum[2];
#pragma unroll
  for (int rr = 0; rr < 2; ++rr) {
    const int r = rh * 2 + rr;
    float s = 0.f;
#pragma unroll
    for (int ww = 0; ww < 8; ++ww) s += red[ww][c2][r][ll];
    gsum[rr] = s;
  }
  __syncthreads();

#pragma unroll
  for (int c = 0; c < 4; ++c)
#pragma unroll
    for (int r = 0; r < 4; ++r)
      red[w][c][r][l] = accU[c][r];
  __syncthreads();
#pragma unroll
  for (int rr = 0; rr < 2; ++rr) {
    const int r = rh * 2 + rr;
    float us = 0.f;
#pragma unroll
    for (int ww = 0; ww < 8; ++ww) us += red[ww][c2][r][ll];
    const float gv = gsum[rr];
    const float hv = gv / (1.f + __expf(-gv)) * us;    // silu(g)*u
    const int m  = c2 * 16 + (ll >> 4) * 4 + r;        // C/D: row=(l>>4)*4+r
    const int ii = n0 + (ll & 15);                     //      col=l&15
    hb[(size_t)m * I_DIM + ii] = f2bf(hv);
  }
}

// ---------------- phase2: down GEMM, split-K x4 (transposed-packed) ----------
__global__ __launch_bounds__(512, 4) void phase2p_kernel(
    const short* __restrict__ hb, const int* __restrict__ dpt,
    const float* __restrict__ dsc, const float* __restrict__ dze,
    float* __restrict__ part)
{
  __shared__ float red[8][4][4][64];   // 32 KB
  const int tile  = blockIdx.x & 255;
  const int split = blockIdx.x >> 8;
  const int n0   = tile * 16;
  const int w    = threadIdx.x >> 6;
  const int l    = threadIdx.x & 63;
  const int col  = l & 15;
  const int krow = l >> 4;
  const int n    = n0 + col;

  const int* dB = dpt + (size_t)tile * (KWI * 16) + col;

  f32x4 acc[4];
#pragma unroll
  for (int c = 0; c < 4; ++c)
#pragma unroll
    for (int r = 0; r < 4; ++r) acc[c][r] = 0.f;

  const int cnt    = (w < 6) ? 11 : 10;
  const int sstart = (w < 6) ? w * 11 : 66 + (w - 6) * 10;
  const int kbase  = split * 2752 + sstart * 32;   // int-element base
  const int wbase  = split * 344 + sstart * 4;     // packed-word base

  // preload the <=4 groups this wave can touch
  const int g0 = kbase >> 7;
  float s0 = dsc[(size_t)n * NGI + g0];
  float s1 = dsc[(size_t)n * NGI + min(g0 + 1, NGI - 1)];
  float s2 = dsc[(size_t)n * NGI + min(g0 + 2, NGI - 1)];
  float s3 = dsc[(size_t)n * NGI + min(g0 + 3, NGI - 1)];
  float z0 = dze[(size_t)n * NGI + g0] * s0;
  float z1 = dze[(size_t)n * NGI + min(g0 + 1, NGI - 1)] * s1;
  float z2 = dze[(size_t)n * NGI + min(g0 + 2, NGI - 1)] * s2;
  float z3 = dze[(size_t)n * NGI + min(g0 + 3, NGI - 1)] * s3;

  int qdA = dB[(wbase + krow) * 16], qdB_;
  short8 aA[4], aB[4];
#pragma unroll
  for (int c = 0; c < 4; ++c)
    aA[c] = *(const short8*)(hb + (size_t)(c * 16 + col) * I_DIM + kbase + krow * 8);

  const int nh = cnt >> 1;
#pragma unroll 1
  for (int u = 0; u < nh; ++u) {
    const int t0 = 2 * u, t1 = 2 * u + 1;
    const int t2 = (t1 + 1 < cnt) ? (t1 + 1) : 0;
    // issue t1 -> B
    qdB_ = dB[(wbase + 4 * t1 + krow) * 16];
#pragma unroll
    for (int c = 0; c < 4; ++c)
      aB[c] = *(const short8*)(hb + (size_t)(c * 16 + col) * I_DIM + kbase + t1 * 32 + krow * 8);
    // compute t0 from A
    {
      const int gi = ((kbase + t0 * 32) >> 7) - g0;
      const float sv = gi == 0 ? s0 : gi == 1 ? s1 : gi == 2 ? s2 : s3;
      const float zv = gi == 0 ? z0 : gi == 1 ? z1 : gi == 2 ? z2 : z3;
      short8 b;
#pragma unroll
      for (int j = 0; j < 8; ++j)
        b[j] = f2bf((float)((qdA >> (4 * j)) & 15) * sv - zv);
#pragma unroll
      for (int c = 0; c < 4; ++c)
        acc[c] = __builtin_amdgcn_mfma_f32_16x16x32_bf16(aA[c], b, acc[c], 0, 0, 0);
    }
    // issue t2 -> A
    qdA = dB[(wbase + 4 * t2 + krow) * 16];
#pragma unroll
    for (int c = 0; c < 4; ++c)
      aA[c] = *(const short8*)(hb + (size_t)(c * 16 + col) * I_DIM + kbase + t2 * 32 + krow * 8);
    // compute t1 from B
    {
      const int gi = ((kbase + t1 * 32) >> 7) - g0;
      const float sv = gi == 0 ? s0 : gi == 1 ? s1 : gi == 2 ? s2 : s3;
      const float zv = gi == 0 ? z0 : gi == 1 ? z1 : gi == 2 ? z2 : z3;
      short8 b;
#pragma unroll
      for (int j = 0; j < 8; ++j)
        b[j] = f2bf((float)((qdB_ >> (4 * j)) & 15) * sv - zv);
#pragma unroll
      for (int c = 0; c < 4; ++c)
        acc[c] = __builtin_amdgcn_mfma_f32_16x16x32_bf16(aB[c], b, acc[c], 0, 0, 0);
    }
  }
  if (cnt & 1) {   // tail (already in A)
    const int t0 = cnt - 1;
    const int gi = ((kbase + t0 * 32) >> 7) - g0;
    const float sv = gi == 0 ? s0 : gi == 1 ? s1 : gi == 2 ? s2 : s3;
    const float zv = gi == 0 ? z0 : gi == 1 ? z1 : gi == 2 ? z2 : z3;
    short8 b;
#pragma unroll
    for (int j = 0; j < 8; ++j)
      b[j] = f2bf((float)((qdA >> (4 * j)) & 15) * sv - zv);
#pragma unroll
    for (int c = 0; c < 4; ++c)
      acc[c] = __builtin_amdgcn_mfma_f32_16x16x32_bf16(aA[c], b, acc[c], 0, 0, 0);
  }

#pragma unroll
  for (int c = 0; c < 4; ++c)
#pragma unroll
    for (int r = 0; r < 4; ++r)
      red[w][c][r][l] = acc[c][r];
  __syncthreads();

  if (threadIdx.x < 256) {
    const int c2 = threadIdx.x >> 6;
    const int ll = threadIdx.x & 63;
    float* po = part + (size_t)split * (64 * H_DIM);
#pragma unroll
    for (int r = 0; r < 4; ++r) {
      float s = 0.f;
#pragma unroll
      for (int ww = 0; ww < 8; ++ww) s += red[ww][c2][r][ll];
      const int m  = c2 * 16 + (ll >> 4) * 4 + r;
      const int nn = n0 + (ll & 15);
      po[(size_t)m * H_DIM + nn] = s;
    }
  }
}

__global__ void reduce4_kernel(const float* __restrict__ part, float* __restrict__ out) {
  const int idx = (blockIdx.x * 256 + threadIdx.x) * 4;
  const int S = 64 * H_DIM;
  f32x4 s0 = *(const f32x4*)(part + idx);
  f32x4 s1 = *(const f32x4*)(part + S + idx);
  f32x4 s2 = *(const f32x4*)(part + 2 * S + idx);
  f32x4 s3 = *(const f32x4*)(part + 3 * S + idx);
  f32x4 r = (s0 + s1) + (s2 + s3);
  *(f32x4*)(out + idx) = r;
}

// ---------------- fallback (raw-weight) kernels, used if ws too small --------
__global__ __launch_bounds__(512, 4) void phase1f_kernel(
    const short* __restrict__ xb,
    const int* __restrict__ gq, const float* __restrict__ gsc, const float* __restrict__ gze,
    const int* __restrict__ uq, const float* __restrict__ usc, const float* __restrict__ uze,
    short* __restrict__ hb)
{
  __shared__ float red[8][4][4][64];
  const int n0   = blockIdx.x * 16;
  const int w    = threadIdx.x >> 6;
  const int l    = threadIdx.x & 63;
  const int col  = l & 15;
  const int krow = l >> 4;
  const int i    = n0 + col;
  const int*   gqr = gq + (size_t)i * H_DIM;
  const int*   uqr = uq + (size_t)i * H_DIM;
  const float* gsr = gsc + (size_t)i * NGH;
  const float* gzr = gze + (size_t)i * NGH;
  const float* usr = usc + (size_t)i * NGH;
  const float* uzr = uze + (size_t)i * NGH;
  f32x4 accG[4], accU[4];
#pragma unroll
  for (int c = 0; c < 4; ++c)
#pragma unroll
    for (int r = 0; r < 4; ++r) { accG[c][r] = 0.f; accU[c][r] = 0.f; }
  const int kw = w * 512;
#pragma unroll 1
  for (int g = 0; g < 4; ++g) {
    const int gg = w * 4 + g;
    const float sg = gsr[gg], zg = gzr[gg] * sg;
    const float su = usr[gg], zu = uzr[gg] * su;
#pragma unroll
    for (int ks = 0; ks < 4; ++ks) {
      const int koff = kw + g * 128 + ks * 32 + krow * 8;
      i32x4 q0 = *(const i32x4*)(gqr + koff);
      i32x4 q1 = *(const i32x4*)(gqr + koff + 4);
      i32x4 p0 = *(const i32x4*)(uqr + koff);
      i32x4 p1 = *(const i32x4*)(uqr + koff + 4);
      short8 a[4];
#pragma unroll
      for (int c = 0; c < 4; ++c)
        a[c] = *(const short8*)(xb + (size_t)(c * 16 + col) * H_DIM + koff);
      short8 bg, bu;
#pragma unroll
      for (int j = 0; j < 4; ++j) {
        bg[j]     = f2bf((float)q0[j] * sg - zg);
        bg[j + 4] = f2bf((float)q1[j] * sg - zg);
        bu[j]     = f2bf((float)p0[j] * su - zu);
        bu[j + 4] = f2bf((float)p1[j] * su - zu);
      }
#pragma unroll
      for (int c = 0; c < 4; ++c) {
        accG[c] = __builtin_amdgcn_mfma_f32_16x16x32_bf16(a[c], bg, accG[c], 0, 0, 0);
        accU[c] = __builtin_amdgcn_mfma_f32_16x16x32_bf16(a[c], bu, accU[c], 0, 0, 0);
      }
    }
  }
  const int c2 = threadIdx.x >> 7;
  const int rh = (threadIdx.x >> 6) & 1;
  const int ll = threadIdx.x & 63;
#pragma unroll
  for (int c = 0; c < 4; ++c)
#pragma unroll
    for (int r = 0; r < 4; ++r)
      red[w][c][r][l] = accG[c][r];
  __syncthreads();
  float gsum[2];
#pragma unroll
  for (int rr = 0; rr < 2; ++rr) {
    const int r = rh * 2 + rr;
    float s = 0.f;
#pragma unroll
    for (int ww = 0; ww < 8; ++ww) s += red[ww][c2][r][ll];
    gsum[rr] = s;
  }
  __syncthreads();
#pragma unroll
  for (int c = 0; c < 4; ++c)
#pragma unroll
    for (int r = 0; r < 4; ++r)
      red[w][c][r][l] = accU[c][r];
  __syncthreads();
#pragma unroll
  for (int rr = 0; rr < 2; ++rr) {
    const int r = rh * 2 + rr;
    float us = 0.f;
#pragma unroll
    for (int ww = 0; ww < 8; ++ww) us += red[ww][c2][r][ll];
    const float gv = gsum[rr];
    const float hv = gv / (1.f + __expf(-gv)) * us;
    const int m  = c2 * 16 + (ll >> 4) * 4 + r;
    const int ii = n0 + (ll & 15);
    hb[(size_t)m * I_DIM + ii] = f2bf(hv);
  }
}

__global__ __launch_bounds__(512, 4) void phase2f_kernel(
    const short* __restrict__ hb,
    const int* __restrict__ dq, const float* __restrict__ dsc, const float* __restrict__ dze,
    float* __restrict__ part)
{
  __shared__ float red[8][4][4][64];
  const int tile  = blockIdx.x & 255;
  const int split = blockIdx.x >> 8;
  const int n0   = tile * 16;
  const int w    = threadIdx.x >> 6;
  const int l    = threadIdx.x & 63;
  const int col  = l & 15;
  const int krow = l >> 4;
  const int n    = n0 + col;
  const int*   dqr = dq + (size_t)n * I_DIM;
  const float* dsr = dsc + (size_t)n * NGI;
  const float* dzr = dze + (size_t)n * NGI;
  f32x4 acc[4];
#pragma unroll
  for (int c = 0; c < 4; ++c)
#pragma unroll
    for (int r = 0; r < 4; ++r) acc[c][r] = 0.f;
  const int cnt    = (w < 6) ? 11 : 10;
  const int sstart = (w < 6) ? w * 11 : 66 + (w - 6) * 10;
  const int kbase  = split * 2752 + sstart * 32;
  int gprev = -1;
  float sv = 0.f, zv = 0.f;
#pragma unroll 1
  for (int s = 0; s < cnt; ++s) {
    const int k0 = kbase + s * 32;
    const int g  = k0 >> 7;
    if (g != gprev) { sv = dsr[g]; zv = dzr[g] * sv; gprev = g; }
    i32x4 q0 = *(const i32x4*)(dqr + k0 + krow * 8);
    i32x4 q1 = *(const i32x4*)(dqr + k0 + krow * 8 + 4);
    short8 a[4];
#pragma unroll
    for (int c = 0; c < 4; ++c)
      a[c] = *(const short8*)(hb + (size_t)(c * 16 + col) * I_DIM + k0 + krow * 8);
    short8 b;
#pragma unroll
    for (int j = 0; j < 4; ++j) {
      b[j]     = f2bf((float)q0[j] * sv - zv);
      b[j + 4] = f2bf((float)q1[j] * sv - zv);
    }
#pragma unroll
    for (int c = 0; c < 4; ++c)
      acc[c] = __builtin_amdgcn_mfma_f32_16x16x32_bf16(a[c], b, acc[c], 0, 0, 0);
  }
#pragma unroll
  for (int c = 0; c < 4; ++c)
#pragma unroll
    for (int r = 0; r < 4; ++r)
      red[w][c][r][l] = acc[c][r];
  __syncthreads();
  if (threadIdx.x < 256) {
    const int c2 = threadIdx.x >> 6;
    const int ll = threadIdx.x & 63;
    float* po = part + (size_t)split * (64 * H_DIM);
#pragma unroll
    for (int r = 0; r < 4; ++r) {
      float s = 0.f;
#pragma unroll
      for (int ww = 0; ww < 8; ++ww) s += red[ww][c2][r][ll];
      const int m  = c2 * 16 + (ll >> 4) * 4 + r;
      const int nn = n0 + (ll & 15);
      po[(size_t)m * H_DIM + nn] = s;
    }
  }
}

extern "C" void kernel_launch(void* const* d_in, const int* in_sizes, int n_in,
                              void* d_out, int out_size, void* d_ws, size_t ws_size,
                              hipStream_t stream) {
  const float* x  = (const float*)d_in[0];
  const int*   gq = (const int*)d_in[1];
  const float* gs = (const float*)d_in[2];
  const float* gz = (const float*)d_in[3];
  const int*   uq = (const int*)d_in[4];
  const float* us = (const float*)d_in[5];
  const float* uz = (const float*)d_in[6];
  const int*   dq = (const int*)d_in[7];
  const float* ds = (const float*)d_in[8];
  const float* dz = (const float*)d_in[9];
  float* out = (float*)d_out;

  const size_t XB   = (size_t)64 * H_DIM * 2;          // 512 KB
  const size_t HB   = (size_t)64 * I_DIM * 2;          // 1.376 MB
  const size_t PART = (size_t)4 * 64 * H_DIM * 4;      // 4 MB
  const size_t PK   = (size_t)NWV * 4;                 // 22.5 MB each

  short* xb   = (short*)d_ws;
  short* hb   = (short*)((char*)d_ws + XB);
  float* part = (float*)((char*)d_ws + XB + HB);
  int*   pkt  = (int*)((char*)d_ws + XB + HB + PART);  // [gate | up | down], pkT order

  xcvt_kernel<<<(64 * H_DIM) / 1024, 256, 0, stream>>>(x, xb);

  if (ws_size >= XB + HB + PART + 3 * PK) {
    packt_kernel<<<33024, 256, 0, stream>>>(gq, uq, dq, pkt);
    phase1p_kernel<<<I_DIM / 16, 512, 0, stream>>>(xb, pkt, gs, gz, us, uz, hb);
    phase2p_kernel<<<(H_DIM / 16) * 4, 512, 0, stream>>>(hb, pkt + 2 * (size_t)NWV, ds, dz, part);
  } else {
    phase1f_kernel<<<I_DIM / 16, 512, 0, stream>>>(xb, gq, gs, gz, uq, us, uz, hb);
    phase2f_kernel<<<(H_DIM / 16) * 4, 512, 0, stream>>>(hb, dq, ds, dz, part);
  }
  reduce4_kernel<<<(64 * H_DIM) / 1024, 256, 0, stream>>>(part, out);
}

// Round 11
// 219.329 us; speedup vs baseline: 1.1241x; 1.0087x over previous
//
#include <hip/hip_runtime.h>
#include <hip/hip_bf16.h>
#include <stdint.h>

#define H_DIM 4096
#define I_DIM 11008
#define NGH   32          // H/128 groups (gate/up)
#define NGI   86          // I/128 groups (down)
#define KWH   512         // packed words per gate/up row (H/8)
#define KWI   1376        // packed words per down row (I/8)
#define NWV   5636096     // packed words per matrix

typedef __attribute__((ext_vector_type(8))) short short8;
typedef __attribute__((ext_vector_type(4))) short s16x4;
typedef __attribute__((ext_vector_type(4))) float f32x4;
typedef __attribute__((ext_vector_type(4))) int   i32x4;

static __device__ __forceinline__ short f2bf(float f) {
  union { __hip_bfloat16 b; short s; } u;
  u.b = __float2bfloat16(f);
  return u.s;
}

// ---- pack one 16-row x 256-int tile -> fragment-ordered pkT[rt][kw][ri] ----
static __device__ __forceinline__ void pack_tile(
    char* smem, const int* __restrict__ src, int RL, int KW,
    int* __restrict__ dstM, int tile)
{
  unsigned short (*sb)[72] = (unsigned short(*)[72])smem;  // stride 72us: low conflict
  int rt, ct;
  if (RL == H_DIM) { rt = tile >> 4; ct = tile & 15; }     // gate/up: 688 x 16
  else             { rt = tile / 43; ct = tile - rt * 43; } // down: 256 x 43
  const int t = threadIdx.x & 255;
  const int rowl = t >> 4, j = t & 15;
  const int* rp = src + (size_t)(rt * 16 + rowl) * RL + ct * 256;
#pragma unroll
  for (int p = 0; p < 4; ++p) {
    i32x4 v = *(const i32x4*)(rp + p * 64 + j * 4);
    sb[rowl][p * 16 + j] = (unsigned short)((v[0] & 15) | ((v[1] & 15) << 4)
                        | ((v[2] & 15) << 8) | ((v[3] & 15) << 12));
  }
  __syncthreads();
  int* dst = dstM + ((size_t)rt * KW + ct * 32) * 16;
#pragma unroll
  for (int p = 0; p < 2; ++p) {
    const int wi = t + p * 256;
    const int kwl = wi >> 4, ri = wi & 15;
    dst[wi] = (int)sb[ri][2 * kwl] | ((int)sb[ri][2 * kwl + 1] << 16);
  }
}

// ---- single-matrix GEMM body (gate: UP=0 writes f32 gsum; up: UP=1 swiglu->hb)
template<int UP>
static __device__ __forceinline__ void gemm_gu_body(
    char* smem, const short* __restrict__ xb, const int* __restrict__ pktM,
    const float* __restrict__ sc, const float* __restrict__ ze,
    float* __restrict__ gsum, short* __restrict__ hb)
{
  float (*red)[4][4][64] = (float(*)[4][4][64])smem;   // [8][4][4][64] = 32 KB
  const int rt   = blockIdx.x;
  const int n0   = rt * 16;
  const int w    = threadIdx.x >> 6;
  const int l    = threadIdx.x & 63;
  const int col  = l & 15;
  const int krow = l >> 4;
  const int i    = n0 + col;

  const int* B = pktM + (size_t)rt * (KWH * 16) + col;

  float sv[4], zv[4];
#pragma unroll
  for (int g = 0; g < 4; ++g) {
    const int gg = w * 4 + g;
    sv[g] = sc[(size_t)i * NGH + gg];
    zv[g] = ze[(size_t)i * NGH + gg] * sv[g];
  }

  f32x4 acc[4];
#pragma unroll
  for (int c = 0; c < 4; ++c)
#pragma unroll
    for (int r = 0; r < 4; ++r) acc[c][r] = 0.f;

  const int wb  = w * 64;
  const int ks0 = w * 512 + krow * 8;

  int qA = B[(wb + krow) * 16], qB;
  short8 aA[4], aB[4];
#pragma unroll
  for (int c = 0; c < 4; ++c)
    aA[c] = *(const short8*)(xb + (size_t)(c * 16 + col) * H_DIM + ks0);

#pragma unroll
  for (int u = 0; u < 8; ++u) {
    const int t1 = 2 * u + 1;
    const int t2 = (2 * u + 2) & 15;   // wraps on last (harmless)
    const int g  = u >> 1;
    qB = B[(wb + 4 * t1 + krow) * 16];
#pragma unroll
    for (int c = 0; c < 4; ++c)
      aB[c] = *(const short8*)(xb + (size_t)(c * 16 + col) * H_DIM + ks0 + t1 * 32);
    {
      short8 b;
#pragma unroll
      for (int j = 0; j < 8; ++j)
        b[j] = f2bf((float)((qA >> (4 * j)) & 15) * sv[g] - zv[g]);
#pragma unroll
      for (int c = 0; c < 4; ++c)
        acc[c] = __builtin_amdgcn_mfma_f32_16x16x32_bf16(aA[c], b, acc[c], 0, 0, 0);
    }
    qA = B[(wb + 4 * t2 + krow) * 16];
#pragma unroll
    for (int c = 0; c < 4; ++c)
      aA[c] = *(const short8*)(xb + (size_t)(c * 16 + col) * H_DIM + ks0 + t2 * 32);
    {
      short8 b;
#pragma unroll
      for (int j = 0; j < 8; ++j)
        b[j] = f2bf((float)((qB >> (4 * j)) & 15) * sv[g] - zv[g]);
#pragma unroll
      for (int c = 0; c < 4; ++c)
        acc[c] = __builtin_amdgcn_mfma_f32_16x16x32_bf16(aB[c], b, acc[c], 0, 0, 0);
    }
  }

#pragma unroll
  for (int c = 0; c < 4; ++c)
#pragma unroll
    for (int r = 0; r < 4; ++r)
      red[w][c][r][l] = acc[c][r];
  __syncthreads();

  const int c2 = threadIdx.x >> 7;
  const int rh = (threadIdx.x >> 6) & 1;
  const int ll = threadIdx.x & 63;
#pragma unroll
  for (int rr = 0; rr < 2; ++rr) {
    const int r = rh * 2 + rr;
    float s = 0.f;
#pragma unroll
    for (int ww = 0; ww < 8; ++ww) s += red[ww][c2][r][ll];
    const int m  = c2 * 16 + (ll >> 4) * 4 + r;   // C/D: row=(l>>4)*4+r
    const int ii = n0 + (ll & 15);                //      col=l&15
    if (UP) {
      const float gv = gsum[(size_t)m * I_DIM + ii];
      const float hv = gv / (1.f + __expf(-gv)) * s;   // silu(g)*u
      hb[(size_t)m * I_DIM + ii] = f2bf(hv);
    } else {
      gsum[(size_t)m * I_DIM + ii] = s;
    }
  }
}

// ---- launch 1: xcvt (blocks 0-127) + pack gate (5504 blocks x 2 tiles) ----
__global__ __launch_bounds__(512, 4) void packG_xcvt_kernel(
    const float* __restrict__ x, short* __restrict__ xb,
    const int* __restrict__ gq, int* __restrict__ gp)
{
  __shared__ char smem[4608];
  if (blockIdx.x < 128) {
    const int i = (blockIdx.x * 512 + threadIdx.x) * 4;
    f32x4 v = *(const f32x4*)(x + i);
    s16x4 o;
    o[0] = f2bf(v[0]); o[1] = f2bf(v[1]); o[2] = f2bf(v[2]); o[3] = f2bf(v[3]);
    *(s16x4*)(xb + i) = o;
    return;
  }
  const int pb = blockIdx.x - 128;
  const int half = threadIdx.x >> 8;
  pack_tile(smem + half * 2304, gq, H_DIM, KWH, gp, pb * 2 + half);
}

// ---- launch 2: gate GEMM (blocks 0-687) || pack up (5504 blocks) ----
__global__ __launch_bounds__(512, 4) void gateU_kernel(
    const short* __restrict__ xb, const int* __restrict__ gp,
    const float* __restrict__ gsc, const float* __restrict__ gze,
    float* __restrict__ gsum, const int* __restrict__ uq, int* __restrict__ upk)
{
  __shared__ char smem[32768];
  if (blockIdx.x < 688) {
    gemm_gu_body<0>(smem, xb, gp, gsc, gze, gsum, nullptr);
    return;
  }
  const int pb = blockIdx.x - 688;
  const int half = threadIdx.x >> 8;
  pack_tile(smem + half * 2304, uq, H_DIM, KWH, upk, pb * 2 + half);
}

// ---- launch 3: up GEMM+SwiGLU (blocks 0-687) || pack down (5504 blocks) ----
__global__ __launch_bounds__(512, 4) void upD_kernel(
    const short* __restrict__ xb, const int* __restrict__ upk,
    const float* __restrict__ usc, const float* __restrict__ uze,
    float* __restrict__ gsum, short* __restrict__ hb,
    const int* __restrict__ dq, int* __restrict__ dpk)
{
  __shared__ char smem[32768];
  if (blockIdx.x < 688) {
    gemm_gu_body<1>(smem, xb, upk, usc, uze, gsum, hb);
    return;
  }
  const int pb = blockIdx.x - 688;
  const int half = threadIdx.x >> 8;
  pack_tile(smem + half * 2304, dq, I_DIM, KWI, dpk, pb * 2 + half);
}

// ---- launch 4: down GEMM, split-K x4 (transposed-packed) ----
__global__ __launch_bounds__(512, 4) void phase2p_kernel(
    const short* __restrict__ hb, const int* __restrict__ dpt,
    const float* __restrict__ dsc, const float* __restrict__ dze,
    float* __restrict__ part)
{
  __shared__ float red[8][4][4][64];   // 32 KB
  const int tile  = blockIdx.x & 255;
  const int split = blockIdx.x >> 8;
  const int n0   = tile * 16;
  const int w    = threadIdx.x >> 6;
  const int l    = threadIdx.x & 63;
  const int col  = l & 15;
  const int krow = l >> 4;
  const int n    = n0 + col;

  const int* dB = dpt + (size_t)tile * (KWI * 16) + col;

  f32x4 acc[4];
#pragma unroll
  for (int c = 0; c < 4; ++c)
#pragma unroll
    for (int r = 0; r < 4; ++r) acc[c][r] = 0.f;

  const int cnt    = (w < 6) ? 11 : 10;
  const int sstart = (w < 6) ? w * 11 : 66 + (w - 6) * 10;
  const int kbase  = split * 2752 + sstart * 32;
  const int wbase  = split * 344 + sstart * 4;

  const int g0 = kbase >> 7;
  float s0 = dsc[(size_t)n * NGI + g0];
  float s1 = dsc[(size_t)n * NGI + min(g0 + 1, NGI - 1)];
  float s2 = dsc[(size_t)n * NGI + min(g0 + 2, NGI - 1)];
  float s3 = dsc[(size_t)n * NGI + min(g0 + 3, NGI - 1)];
  float z0 = dze[(size_t)n * NGI + g0] * s0;
  float z1 = dze[(size_t)n * NGI + min(g0 + 1, NGI - 1)] * s1;
  float z2 = dze[(size_t)n * NGI + min(g0 + 2, NGI - 1)] * s2;
  float z3 = dze[(size_t)n * NGI + min(g0 + 3, NGI - 1)] * s3;

  int qdA = dB[(wbase + krow) * 16], qdB_;
  short8 aA[4], aB[4];
#pragma unroll
  for (int c = 0; c < 4; ++c)
    aA[c] = *(const short8*)(hb + (size_t)(c * 16 + col) * I_DIM + kbase + krow * 8);

  const int nh = cnt >> 1;
#pragma unroll 1
  for (int u = 0; u < nh; ++u) {
    const int t0 = 2 * u, t1 = 2 * u + 1;
    const int t2 = (t1 + 1 < cnt) ? (t1 + 1) : 0;
    qdB_ = dB[(wbase + 4 * t1 + krow) * 16];
#pragma unroll
    for (int c = 0; c < 4; ++c)
      aB[c] = *(const short8*)(hb + (size_t)(c * 16 + col) * I_DIM + kbase + t1 * 32 + krow * 8);
    {
      const int gi = ((kbase + t0 * 32) >> 7) - g0;
      const float sv = gi == 0 ? s0 : gi == 1 ? s1 : gi == 2 ? s2 : s3;
      const float zv = gi == 0 ? z0 : gi == 1 ? z1 : gi == 2 ? z2 : z3;
      short8 b;
#pragma unroll
      for (int j = 0; j < 8; ++j)
        b[j] = f2bf((float)((qdA >> (4 * j)) & 15) * sv - zv);
#pragma unroll
      for (int c = 0; c < 4; ++c)
        acc[c] = __builtin_amdgcn_mfma_f32_16x16x32_bf16(aA[c], b, acc[c], 0, 0, 0);
    }
    qdA = dB[(wbase + 4 * t2 + krow) * 16];
#pragma unroll
    for (int c = 0; c < 4; ++c)
      aA[c] = *(const short8*)(hb + (size_t)(c * 16 + col) * I_DIM + kbase + t2 * 32 + krow * 8);
    {
      const int gi = ((kbase + t1 * 32) >> 7) - g0;
      const float sv = gi == 0 ? s0 : gi == 1 ? s1 : gi == 2 ? s2 : s3;
      const float zv = gi == 0 ? z0 : gi == 1 ? z1 : gi == 2 ? z2 : z3;
      short8 b;
#pragma unroll
      for (int j = 0; j < 8; ++j)
        b[j] = f2bf((float)((qdB_ >> (4 * j)) & 15) * sv - zv);
#pragma unroll
      for (int c = 0; c < 4; ++c)
        acc[c] = __builtin_amdgcn_mfma_f32_16x16x32_bf16(aB[c], b, acc[c], 0, 0, 0);
    }
  }
  if (cnt & 1) {
    const int t0 = cnt - 1;
    const int gi = ((kbase + t0 * 32) >> 7) - g0;
    const float sv = gi == 0 ? s0 : gi == 1 ? s1 : gi == 2 ? s2 : s3;
    const float zv = gi == 0 ? z0 : gi == 1 ? z1 : gi == 2 ? z2 : z3;
    short8 b;
#pragma unroll
    for (int j = 0; j < 8; ++j)
      b[j] = f2bf((float)((qdA >> (4 * j)) & 15) * sv - zv);
#pragma unroll
    for (int c = 0; c < 4; ++c)
      acc[c] = __builtin_amdgcn_mfma_f32_16x16x32_bf16(aA[c], b, acc[c], 0, 0, 0);
  }

#pragma unroll
  for (int c = 0; c < 4; ++c)
#pragma unroll
    for (int r = 0; r < 4; ++r)
      red[w][c][r][l] = acc[c][r];
  __syncthreads();

  if (threadIdx.x < 256) {
    const int c2 = threadIdx.x >> 6;
    const int ll = threadIdx.x & 63;
    float* po = part + (size_t)split * (64 * H_DIM);
#pragma unroll
    for (int r = 0; r < 4; ++r) {
      float s = 0.f;
#pragma unroll
      for (int ww = 0; ww < 8; ++ww) s += red[ww][c2][r][ll];
      const int m  = c2 * 16 + (ll >> 4) * 4 + r;
      const int nn = n0 + (ll & 15);
      po[(size_t)m * H_DIM + nn] = s;
    }
  }
}

__global__ void reduce4_kernel(const float* __restrict__ part, float* __restrict__ out) {
  const int idx = (blockIdx.x * 256 + threadIdx.x) * 4;
  const int S = 64 * H_DIM;
  f32x4 s0 = *(const f32x4*)(part + idx);
  f32x4 s1 = *(const f32x4*)(part + S + idx);
  f32x4 s2 = *(const f32x4*)(part + 2 * S + idx);
  f32x4 s3 = *(const f32x4*)(part + 3 * S + idx);
  f32x4 r = (s0 + s1) + (s2 + s3);
  *(f32x4*)(out + idx) = r;
}

// ---------------- fallback (raw-weight) kernels, used if ws too small --------
__global__ void xcvt_kernel(const float* __restrict__ x, short* __restrict__ xb) {
  int i = (blockIdx.x * 256 + threadIdx.x) * 4;
  f32x4 v = *(const f32x4*)(x + i);
  s16x4 o;
  o[0] = f2bf(v[0]); o[1] = f2bf(v[1]); o[2] = f2bf(v[2]); o[3] = f2bf(v[3]);
  *(s16x4*)(xb + i) = o;
}

__global__ __launch_bounds__(512, 4) void phase1f_kernel(
    const short* __restrict__ xb,
    const int* __restrict__ gq, const float* __restrict__ gsc, const float* __restrict__ gze,
    const int* __restrict__ uq, const float* __restrict__ usc, const float* __restrict__ uze,
    short* __restrict__ hb)
{
  __shared__ float red[8][4][4][64];
  const int n0   = blockIdx.x * 16;
  const int w    = threadIdx.x >> 6;
  const int l    = threadIdx.x & 63;
  const int col  = l & 15;
  const int krow = l >> 4;
  const int i    = n0 + col;
  const int*   gqr = gq + (size_t)i * H_DIM;
  const int*   uqr = uq + (size_t)i * H_DIM;
  const float* gsr = gsc + (size_t)i * NGH;
  const float* gzr = gze + (size_t)i * NGH;
  const float* usr = usc + (size_t)i * NGH;
  const float* uzr = uze + (size_t)i * NGH;
  f32x4 accG[4], accU[4];
#pragma unroll
  for (int c = 0; c < 4; ++c)
#pragma unroll
    for (int r = 0; r < 4; ++r) { accG[c][r] = 0.f; accU[c][r] = 0.f; }
  const int kw = w * 512;
#pragma unroll 1
  for (int g = 0; g < 4; ++g) {
    const int gg = w * 4 + g;
    const float sg = gsr[gg], zg = gzr[gg] * sg;
    const float su = usr[gg], zu = uzr[gg] * su;
#pragma unroll
    for (int ks = 0; ks < 4; ++ks) {
      const int koff = kw + g * 128 + ks * 32 + krow * 8;
      i32x4 q0 = *(const i32x4*)(gqr + koff);
      i32x4 q1 = *(const i32x4*)(gqr + koff + 4);
      i32x4 p0 = *(const i32x4*)(uqr + koff);
      i32x4 p1 = *(const i32x4*)(uqr + koff + 4);
      short8 a[4];
#pragma unroll
      for (int c = 0; c < 4; ++c)
        a[c] = *(const short8*)(xb + (size_t)(c * 16 + col) * H_DIM + koff);
      short8 bg, bu;
#pragma unroll
      for (int j = 0; j < 4; ++j) {
        bg[j]     = f2bf((float)q0[j] * sg - zg);
        bg[j + 4] = f2bf((float)q1[j] * sg - zg);
        bu[j]     = f2bf((float)p0[j] * su - zu);
        bu[j + 4] = f2bf((float)p1[j] * su - zu);
      }
#pragma unroll
      for (int c = 0; c < 4; ++c) {
        accG[c] = __builtin_amdgcn_mfma_f32_16x16x32_bf16(a[c], bg, accG[c], 0, 0, 0);
        accU[c] = __builtin_amdgcn_mfma_f32_16x16x32_bf16(a[c], bu, accU[c], 0, 0, 0);
      }
    }
  }
  const int c2 = threadIdx.x >> 7;
  const int rh = (threadIdx.x >> 6) & 1;
  const int ll = threadIdx.x & 63;
#pragma unroll
  for (int c = 0; c < 4; ++c)
#pragma unroll
    for (int r = 0; r < 4; ++r)
      red[w][c][r][l] = accG[c][r];
  __syncthreads();
  float gsum[2];
#pragma unroll
  for (int rr = 0; rr < 2; ++rr) {
    const int r = rh * 2 + rr;
    float s = 0.f;
#pragma unroll
    for (int ww = 0; ww < 8; ++ww) s += red[ww][c2][r][ll];
    gsum[rr] = s;
  }
  __syncthreads();
#pragma unroll
  for (int c = 0; c < 4; ++c)
#pragma unroll
    for (int r = 0; r < 4; ++r)
      red[w][c][r][l] = accU[c][r];
  __syncthreads();
#pragma unroll
  for (int rr = 0; rr < 2; ++rr) {
    const int r = rh * 2 + rr;
    float us = 0.f;
#pragma unroll
    for (int ww = 0; ww < 8; ++ww) us += red[ww][c2][r][ll];
    const float gv = gsum[rr];
    const float hv = gv / (1.f + __expf(-gv)) * us;
    const int m  = c2 * 16 + (ll >> 4) * 4 + r;
    const int ii = n0 + (ll & 15);
    hb[(size_t)m * I_DIM + ii] = f2bf(hv);
  }
}

__global__ __launch_bounds__(512, 4) void phase2f_kernel(
    const short* __restrict__ hb,
    const int* __restrict__ dq, const float* __restrict__ dsc, const float* __restrict__ dze,
    float* __restrict__ part)
{
  __shared__ float red[8][4][4][64];
  const int tile  = blockIdx.x & 255;
  const int split = blockIdx.x >> 8;
  const int n0   = tile * 16;
  const int w    = threadIdx.x >> 6;
  const int l    = threadIdx.x & 63;
  const int col  = l & 15;
  const int krow = l >> 4;
  const int n    = n0 + col;
  const int*   dqr = dq + (size_t)n * I_DIM;
  const float* dsr = dsc + (size_t)n * NGI;
  const float* dzr = dze + (size_t)n * NGI;
  f32x4 acc[4];
#pragma unroll
  for (int c = 0; c < 4; ++c)
#pragma unroll
    for (int r = 0; r < 4; ++r) acc[c][r] = 0.f;
  const int cnt    = (w < 6) ? 11 : 10;
  const int sstart = (w < 6) ? w * 11 : 66 + (w - 6) * 10;
  const int kbase  = split * 2752 + sstart * 32;
  int gprev = -1;
  float sv = 0.f, zv = 0.f;
#pragma unroll 1
  for (int s = 0; s < cnt; ++s) {
    const int k0 = kbase + s * 32;
    const int g  = k0 >> 7;
    if (g != gprev) { sv = dsr[g]; zv = dzr[g] * sv; gprev = g; }
    i32x4 q0 = *(const i32x4*)(dqr + k0 + krow * 8);
    i32x4 q1 = *(const i32x4*)(dqr + k0 + krow * 8 + 4);
    short8 a[4];
#pragma unroll
    for (int c = 0; c < 4; ++c)
      a[c] = *(const short8*)(hb + (size_t)(c * 16 + col) * I_DIM + k0 + krow * 8);
    short8 b;
#pragma unroll
    for (int j = 0; j < 4; ++j) {
      b[j]     = f2bf((float)q0[j] * sv - zv);
      b[j + 4] = f2bf((float)q1[j] * sv - zv);
    }
#pragma unroll
    for (int c = 0; c < 4; ++c)
      acc[c] = __builtin_amdgcn_mfma_f32_16x16x32_bf16(a[c], b, acc[c], 0, 0, 0);
  }
#pragma unroll
  for (int c = 0; c < 4; ++c)
#pragma unroll
    for (int r = 0; r < 4; ++r)
      red[w][c][r][l] = acc[c][r];
  __syncthreads();
  if (threadIdx.x < 256) {
    const int c2 = threadIdx.x >> 6;
    const int ll = threadIdx.x & 63;
    float* po = part + (size_t)split * (64 * H_DIM);
#pragma unroll
    for (int r = 0; r < 4; ++r) {
      float s = 0.f;
#pragma unroll
      for (int ww = 0; ww < 8; ++ww) s += red[ww][c2][r][ll];
      const int m  = c2 * 16 + (ll >> 4) * 4 + r;
      const int nn = n0 + (ll & 15);
      po[(size_t)m * H_DIM + nn] = s;
    }
  }
}

extern "C" void kernel_launch(void* const* d_in, const int* in_sizes, int n_in,
                              void* d_out, int out_size, void* d_ws, size_t ws_size,
                              hipStream_t stream) {
  const float* x  = (const float*)d_in[0];
  const int*   gq = (const int*)d_in[1];
  const float* gs = (const float*)d_in[2];
  const float* gz = (const float*)d_in[3];
  const int*   uq = (const int*)d_in[4];
  const float* us = (const float*)d_in[5];
  const float* uz = (const float*)d_in[6];
  const int*   dq = (const int*)d_in[7];
  const float* ds = (const float*)d_in[8];
  const float* dz = (const float*)d_in[9];
  float* out = (float*)d_out;

  const size_t XB   = (size_t)64 * H_DIM * 2;          // 512 KB
  const size_t HB   = (size_t)64 * I_DIM * 2;          // 1.376 MB
  const size_t PART = (size_t)4 * 64 * H_DIM * 4;      // 4 MB (also reused as gsum 2.82MB)
  const size_t PK   = (size_t)NWV * 4;                 // 22.5 MB each

  short* xb   = (short*)d_ws;
  short* hb   = (short*)((char*)d_ws + XB);
  float* part = (float*)((char*)d_ws + XB + HB);       // gsum during launches 2-3
  int*   pkt  = (int*)((char*)d_ws + XB + HB + PART);
  int*   gp   = pkt;
  int*   upk  = pkt + (size_t)NWV;
  int*   dpk  = pkt + 2 * (size_t)NWV;

  if (ws_size >= XB + HB + PART + 3 * PK) {
    packG_xcvt_kernel<<<128 + 5504, 512, 0, stream>>>(x, xb, gq, gp);
    gateU_kernel<<<688 + 5504, 512, 0, stream>>>(xb, gp, gs, gz, part, uq, upk);
    upD_kernel<<<688 + 5504, 512, 0, stream>>>(xb, upk, us, uz, part, hb, dq, dpk);
    phase2p_kernel<<<(H_DIM / 16) * 4, 512, 0, stream>>>(hb, dpk, ds, dz, part);
  } else {
    xcvt_kernel<<<(64 * H_DIM) / 1024, 256, 0, stream>>>(x, xb);
    phase1f_kernel<<<I_DIM / 16, 512, 0, stream>>>(xb, gq, gs, gz, uq, us, uz, hb);
    phase2f_kernel<<<(H_DIM / 16) * 4, 512, 0, stream>>>(hb, dq, ds, dz, part);
  }
  reduce4_kernel<<<(64 * H_DIM) / 1024, 256, 0, stream>>>(part, out);
}